// Round 8
// baseline (329.582 us; speedup 1.0000x reference)
//
#include <hip/hip_runtime.h>
#include <hip/hip_bf16.h>

#define B_   32
#define L_   2048
#define CIN  256
#define HID  512
#define TL   64
#define NLT  (L_ / TL)        // 32 tiles per batch
#define NTILES (B_ * NLT)     // 1024
#define TPB   4               // tiles per persistent block
#define NBLK  (NTILES / TPB)  // 256 blocks = 1 per CU

// Padded LDS row strides: stride/4 % 32 == 8 -> consecutive rows land on
// rotated bank phases, making the fragment ds_read_b128 conflict-free
// (R7 measured 4-way conflicts with 512/1024-B strides: bank depended only
// on (l4*16)^(l15*16) = 16 patterns over 64 lanes).
#define ASTR 544              // A row: 256 bf16 = 512 B + 32 pad
#define HSTR 1056             // H row: 512 bf16 = 1024 B + 32 pad

// LDS map (134 KB): A(x)@0, A(y)@34816 (together 69632); Hy ALIASES the A
// region (67584 <= 69632; A dead after gemm1, Hy dead before A[t+1] write);
// Hx separate @69632.
#define AX_OFF 0u
#define AY_OFF ((unsigned)(64 * ASTR))        // 34816
#define HY_OFF 0u
#define HX_OFF ((unsigned)(2 * 64 * ASTR))    // 69632
#define LDS_BYTES (2 * 64 * ASTR + 64 * HSTR) // 137216

typedef __bf16 bf16_t;
typedef __bf16 bf16x8 __attribute__((ext_vector_type(8)));
typedef __bf16 bf16x4 __attribute__((ext_vector_type(4)));
typedef float  f32x4  __attribute__((ext_vector_type(4)));

__device__ __forceinline__ float fast_tanh(float v) {
    float xx = fminf(fmaxf(v, -9.0f), 9.0f);
    float e = exp2f(xx * 2.885390081777927f);          // e^{2x}
    return (e - 1.0f) * __builtin_amdgcn_rcpf(e + 1.0f);
}

// lgkmcnt-only barrier: waits LDS ops, does NOT drain vmcnt -> global loads
// issued before it stay in flight across the barrier (the T3/T4 idea).
// Single volatile asm with memory clobber = two-sided compiler fence.
__device__ __forceinline__ void lgkm_bar() {
    asm volatile("s_waitcnt lgkmcnt(0)\n\ts_barrier" ::: "memory");
}

// ---------------------------------------------------------------------------
// Kernel 1: cast weights fp32 -> bf16 into workspace
// ---------------------------------------------------------------------------
__global__ void cast_weights_kernel(const float* __restrict__ W1, const float* __restrict__ W2,
                                    bf16_t* __restrict__ W1b, bf16_t* __restrict__ W2b)
{
    int i = blockIdx.x * blockDim.x + threadIdx.x;
    if (i < HID * CIN) W1b[i] = (bf16_t)W1[i];
    if (i < HID * HID) W2b[i] = (bf16_t)W2[i];
}

// ---------------------------------------------------------------------------
// Kernel 2: persistent fused kernel. 256 blocks x 1024 threads (16 waves),
// TPB=4 consecutive 64-row tiles per block. Per tile:
//   gemm1(x,y | shared W1) -> B0 -> [issue A(t+1) half1] writeH -> B1 ->
//   gemm2(y-pass) -> ty stash -> B2 -> [write half1, issue half2]
//   gemm2(x-pass) -> product/reduce/store -> [write half2] -> B3
// Staging loads fly across lgkm-only barriers under the gemm2 passes.
// Reg ledger: gemm1 peak = 64 AGPR acc + ~64 arch = 128 (4-wave/SIMD cap);
// gemm2 phases: 32 acc + 16 ty + 16 stage + w8 < 128.
// ---------------------------------------------------------------------------
__global__ __launch_bounds__(1024, 4)
void fused_proj_kernel(const float* __restrict__ x, const float* __restrict__ y,
                       const bf16_t* __restrict__ W1b, const float* __restrict__ b1,
                       const bf16_t* __restrict__ W2b, const float* __restrict__ b2,
                       float* __restrict__ partial)
{
    __shared__ char U[LDS_BYTES];

    const int tid  = threadIdx.x;
    const int lane = tid & 63;
    const int wv   = tid >> 6;           // wave 0..15
    const int l15  = lane & 15;
    const int l4   = lane >> 4;
    const int col0 = wv * 32;            // this wave's output-col base

    // staging identity: threads 0-511 stage x, 512-1023 stage y; 8 thr/row
    const int sp  = tid >> 9;
    const int t9  = tid & 511;
    const int sr  = t9 >> 3;             // row 0..63
    const int sq  = t9 & 7;              // float4 slot
    const unsigned sswz  = (unsigned)((sr & 15) << 4);
    const unsigned sldsb = (sp ? AY_OFF : AX_OFF) + (unsigned)(sr * ASTR);

    const int tile0 = blockIdx.x * TPB;  // TPB tiles never cross a batch (32%4==0)
    const float* sptr = (sp ? y : x) +
        ((size_t)(tile0 >> 5) * L_ + (size_t)(tile0 & 31) * TL + sr) * CIN;
    float* pptr = partial + (size_t)tile0 * HID + col0;

    auto sload = [&](const float* base, int half, float4 (&v)[4]) {
        const float4* s4 = reinterpret_cast<const float4*>(base);
#pragma unroll
        for (int c = 0; c < 4; ++c) v[c] = s4[sq + 8 * (half * 4 + c)];
    };
    auto swrite = [&](int half, float4 (&v)[4]) {
        char* rowp = U + sldsb;
#pragma unroll
        for (int c = 0; c < 4; ++c) {
            const int f = sq + 8 * (half * 4 + c);
            bf16x4 h;
            h[0] = (bf16_t)v[c].x; h[1] = (bf16_t)v[c].y;
            h[2] = (bf16_t)v[c].z; h[3] = (bf16_t)v[c].w;
            *reinterpret_cast<bf16x4*>(rowp + (((unsigned)(8 * f)) ^ sswz)) = h;
        }
    };

    // gemm2 pass over one pipeline's H (K=HID), bias b2 folded into init
    auto gemm2pass = [&](unsigned hbase, f32x4 (&acc)[4][2]) {
#pragma unroll
        for (int cj = 0; cj < 2; ++cj) {
            float4 bv = *reinterpret_cast<const float4*>(b2 + col0 + cj * 16 + l4 * 4);
            f32x4 bi = (f32x4){bv.x, bv.y, bv.z, bv.w};
#pragma unroll
            for (int ri = 0; ri < 4; ++ri) acc[ri][cj] = bi;
        }
        for (int kk = 0; kk < HID / 32; ++kk) {
            bf16x8 w[2];
#pragma unroll
            for (int cj = 0; cj < 2; ++cj)
                w[cj] = *reinterpret_cast<const bf16x8*>(
                    W2b + (size_t)(col0 + cj * 16 + l15) * HID + kk * 32 + l4 * 8);
            __builtin_amdgcn_s_setprio(1);
#pragma unroll
            for (int ri = 0; ri < 4; ++ri) {
                const int r = ri * 16 + l15;
                unsigned off = (unsigned)(r * HSTR) +
                               (((unsigned)(kk * 64 + l4 * 16)) ^ ((unsigned)((r & 15) << 4)));
                bf16x8 p = *reinterpret_cast<const bf16x8*>(U + hbase + off);
#pragma unroll
                for (int cj = 0; cj < 2; ++cj)
                    acc[ri][cj] = __builtin_amdgcn_mfma_f32_16x16x32_bf16(w[cj], p, acc[ri][cj], 0, 0, 0);
            }
            __builtin_amdgcn_s_setprio(0);
        }
    };

    // ---- prologue: stage tile0
    {
        float4 v1[4], v2[4];
        sload(sptr, 0, v1);
        sload(sptr, 1, v2);
        swrite(0, v1);
        swrite(1, v2);
    }
    lgkm_bar();

    for (int t = 0; t < TPB; ++t) {
        const bool pf = (t + 1 < TPB);
        const float* nptr = sptr + TL * CIN;
        float4 v[4];

        // ---- GEMM1 both pipes (shared W1 stream), bias b1 folded into init
        f32x4 accx[4][2], accy[4][2];
#pragma unroll
        for (int cj = 0; cj < 2; ++cj) {
            float4 bv = *reinterpret_cast<const float4*>(b1 + col0 + cj * 16 + l4 * 4);
            f32x4 bi = (f32x4){bv.x, bv.y, bv.z, bv.w};
#pragma unroll
            for (int ri = 0; ri < 4; ++ri) { accx[ri][cj] = bi; accy[ri][cj] = bi; }
        }
        for (int kk = 0; kk < CIN / 32; ++kk) {
            bf16x8 w[2];
#pragma unroll
            for (int cj = 0; cj < 2; ++cj)
                w[cj] = *reinterpret_cast<const bf16x8*>(
                    W1b + (size_t)(col0 + cj * 16 + l15) * CIN + kk * 32 + l4 * 8);
            __builtin_amdgcn_s_setprio(1);
#pragma unroll
            for (int ri = 0; ri < 4; ++ri) {
                const int r = ri * 16 + l15;
                unsigned off = (unsigned)(r * ASTR) +
                               (((unsigned)(kk * 64 + l4 * 16)) ^ ((unsigned)((r & 15) << 4)));
                bf16x8 ax = *reinterpret_cast<const bf16x8*>(U + AX_OFF + off);
                bf16x8 ay = *reinterpret_cast<const bf16x8*>(U + AY_OFF + off);
#pragma unroll
                for (int cj = 0; cj < 2; ++cj) {
                    accx[ri][cj] = __builtin_amdgcn_mfma_f32_16x16x32_bf16(w[cj], ax, accx[ri][cj], 0, 0, 0);
                    accy[ri][cj] = __builtin_amdgcn_mfma_f32_16x16x32_bf16(w[cj], ay, accy[ri][cj], 0, 0, 0);
                }
            }
            __builtin_amdgcn_s_setprio(0);
        }
        lgkm_bar();                      // B0: all A reads done (Hy may clobber)

        if (pf) sload(nptr, 0, v);       // issue half1 early; flies across B1

        // ---- writeH: Hx -> HX region, Hy -> A region (packed b64, swizzled)
#pragma unroll
        for (int ri = 0; ri < 4; ++ri) {
            const int r = ri * 16 + l15;
            const unsigned swz = (unsigned)((r & 15) << 4);
#pragma unroll
            for (int cj = 0; cj < 2; ++cj) {
                unsigned off = (unsigned)(r * HSTR) +
                               (((unsigned)((col0 + cj * 16 + l4 * 4) * 2)) ^ swz);
                bf16x4 px, py;
#pragma unroll
                for (int r2 = 0; r2 < 4; ++r2) {
                    px[r2] = (bf16_t)accx[ri][cj][r2];
                    py[r2] = (bf16_t)accy[ri][cj][r2];
                }
                *reinterpret_cast<bf16x4*>(U + HX_OFF + off) = px;
                *reinterpret_cast<bf16x4*>(U + HY_OFF + off) = py;
            }
        }
        lgkm_bar();                      // B1: H visible (vmcnt NOT drained)

        // ---- GEMM2 y-pass -> ty stash (bf16)
        f32x4 acc2[4][2];
        gemm2pass(HY_OFF, acc2);
        bf16x4 ty[4][2];
#pragma unroll
        for (int ri = 0; ri < 4; ++ri)
#pragma unroll
            for (int cj = 0; cj < 2; ++cj)
#pragma unroll
                for (int r2 = 0; r2 < 4; ++r2)
                    ty[ri][cj][r2] = (bf16_t)fast_tanh(acc2[ri][cj][r2]);
        lgkm_bar();                      // B2: Hy reads done (A region free)

        if (pf) {
            swrite(0, v);                // A(t+1) half1 -> A region
            sload(nptr, 1, v);           // issue half2; flies under gemm2(x)
        }

        // ---- GEMM2 x-pass + product + reduce
        gemm2pass(HX_OFF, acc2);
        f32x4 psum[2];
        psum[0] = (f32x4){0.f, 0.f, 0.f, 0.f};
        psum[1] = (f32x4){0.f, 0.f, 0.f, 0.f};
#pragma unroll
        for (int ri = 0; ri < 4; ++ri)
#pragma unroll
            for (int cj = 0; cj < 2; ++cj)
#pragma unroll
                for (int r2 = 0; r2 < 4; ++r2) {
                    float tx = fast_tanh(acc2[ri][cj][r2]);
                    psum[cj][r2] += tx * (float)ty[ri][cj][r2];
                }
#pragma unroll
        for (int cj = 0; cj < 2; ++cj)
#pragma unroll
            for (int r2 = 0; r2 < 4; ++r2) {
                float s = psum[cj][r2];
                s += __shfl_xor(s, 1);
                s += __shfl_xor(s, 2);
                s += __shfl_xor(s, 4);
                s += __shfl_xor(s, 8);
                psum[cj][r2] = s;
            }
        if (l15 == 0) {
#pragma unroll
            for (int cj = 0; cj < 2; ++cj) {
                float4 o = make_float4(psum[cj][0], psum[cj][1], psum[cj][2], psum[cj][3]);
                *reinterpret_cast<float4*>(pptr + cj * 16 + l4 * 4) = o;
            }
        }

        if (pf) swrite(1, v);            // A(t+1) half2 (vmcnt waited on v use)
        lgkm_bar();                      // B3: A(t+1) ready for next gemm1

        sptr = nptr;
        pptr += HID;
    }
}

// ---------------------------------------------------------------------------
// Kernel 3: sum the 32 l-tile partials per batch -> out[B][HID]
// ---------------------------------------------------------------------------
__global__ void reduce_kernel(const float* __restrict__ partial, float* __restrict__ out)
{
    int b = blockIdx.x;
    int g = threadIdx.x;             // 512 threads
    float s = 0.f;
#pragma unroll
    for (int t = 0; t < NLT; ++t)
        s += partial[((size_t)(b * NLT + t)) * HID + g];
    out[b * HID + g] = s;
}

extern "C" void kernel_launch(void* const* d_in, const int* in_sizes, int n_in,
                              void* d_out, int out_size, void* d_ws, size_t ws_size,
                              hipStream_t stream)
{
    const float* x  = (const float*)d_in[0];
    const float* y  = (const float*)d_in[1];
    const float* W1 = (const float*)d_in[2];
    const float* b1 = (const float*)d_in[3];
    const float* W2 = (const float*)d_in[4];
    const float* b2 = (const float*)d_in[5];
    float* out = (float*)d_out;

    char* ws = (char*)d_ws;
    bf16_t* W1b    = (bf16_t*)ws;                    // 256 KB
    bf16_t* W2b    = (bf16_t*)(ws + (256 << 10));    // 512 KB
    float*  partial = (float*)(ws + (768 << 10));    // 2 MB (1024 tiles x 512)

    hipLaunchKernelGGL(cast_weights_kernel, dim3(1024), dim3(256), 0, stream, W1, W2, W1b, W2b);
    hipLaunchKernelGGL(fused_proj_kernel, dim3(NBLK), dim3(1024), 0, stream,
                       x, y, W1b, b1, W2b, b2, partial);
    hipLaunchKernelGGL(reduce_kernel, dim3(B_), dim3(512), 0, stream, partial, out);
}